// Round 2
// baseline (1621.079 us; speedup 1.0000x reference)
//
#include <hip/hip_runtime.h>

// Conv2d 3x3 s1 p1, NCHW fp32: N=32, Cin=256, H=W=56, Cout=256.
// Baseline: direct conv, implicit-GEMM tiling, fp32 VALU (no fp32 MFMA on CDNA4).
// Block tile: 128 out-channels x (8x8 spatial) for one n. K-step: 8 input channels.

#define NB   32
#define CIN  256
#define HH   56
#define WW   56
#define COUT 256

#define BM   128   // out-channels per block
#define KC   8     // input channels per K-step

__global__ __launch_bounds__(256, 3) void conv3x3_f32(
    const float* __restrict__ x,      // [N][CIN][56][56]
    const float* __restrict__ wgt,    // [COUT][CIN][3][3]
    const float* __restrict__ bias,   // [COUT]
    float* __restrict__ y)            // [N][COUT][56][56]
{
    // sW[k][co]: k = ci_local*9 + kh*3 + kw (0..71), co = 0..127. 36 KB.
    __shared__ float sW[KC * 9][BM];
    // Input patch: [ci_local][10 rows][12 cols(pad)] — rows padded 10->12 so
    // 4-float groups at col 0/4 are 16B aligned for ds_read_b128. 3.75 KB.
    __shared__ float sX[KC][10][12];

    const int t   = threadIdx.x;
    const int tco = t >> 4;          // 0..15 : which 8-co group
    const int tsp = t & 15;          // 0..15 : which 4-spatial group
    const int srow  = tsp >> 1;      // 0..7
    const int scol0 = (tsp & 1) * 4; // 0 or 4

    // grid: [co_t(2)][spatial(49)][n(32)]
    const int bid  = blockIdx.x;
    const int co_t = bid / (49 * NB);
    const int rem  = bid % (49 * NB);
    const int sp_t = rem / NB;
    const int n    = rem % NB;
    const int h0   = (sp_t / 7) * 8;
    const int w0   = (sp_t % 7) * 8;
    const int co0  = co_t * BM;

    float acc[8][4];
    #pragma unroll
    for (int r = 0; r < 8; ++r)
        #pragma unroll
        for (int j = 0; j < 4; ++j) acc[r][j] = 0.f;

    // Weight source for this thread: co = co0 + t/2, half = t&1 covers 36 floats
    // (contiguous in [ci][kh][kw]), 16B-aligned (ci0*9 and half*36 are mult of 4).
    const int co_l  = t >> 1;
    const int half  = t & 1;

    for (int ci0 = 0; ci0 < CIN; ci0 += KC) {
        __syncthreads();   // protect previous iteration's LDS reads

        // ---- stage weights: 128 co x 8 ci x 9 = 9216 floats ----
        {
            const float4* wsrc = reinterpret_cast<const float4*>(
                wgt + (size_t)(co0 + co_l) * (CIN * 9) + ci0 * 9 + half * 36);
            #pragma unroll
            for (int q = 0; q < 9; ++q) {
                float4 v = wsrc[q];
                const int k0 = half * 36 + q * 4;
                sW[k0 + 0][co_l] = v.x;
                sW[k0 + 1][co_l] = v.y;
                sW[k0 + 2][co_l] = v.z;
                sW[k0 + 3][co_l] = v.w;
            }
        }

        // ---- stage input patch: 8 ci x 10 x 10 (halo, zero-padded) ----
        for (int idx = t; idx < KC * 100; idx += 256) {
            const int c  = idx / 100;
            const int r  = (idx % 100) / 10;
            const int cc = idx % 10;
            const int hh = h0 + r - 1;
            const int ww = w0 + cc - 1;
            float v = 0.f;
            if (hh >= 0 && hh < HH && ww >= 0 && ww < WW)
                v = x[(((size_t)n * CIN + (ci0 + c)) * HH + hh) * WW + ww];
            sX[c][r][cc] = v;
        }

        __syncthreads();

        // ---- compute: 8 ci x 3 kh x 3 kw, 8x4 register tile ----
        for (int c = 0; c < KC; ++c) {
            #pragma unroll
            for (int kh = 0; kh < 3; ++kh) {
                float xw[8];
                *reinterpret_cast<float4*>(&xw[0]) =
                    *reinterpret_cast<const float4*>(&sX[c][srow + kh][scol0]);
                *reinterpret_cast<float4*>(&xw[4]) =
                    *reinterpret_cast<const float4*>(&sX[c][srow + kh][scol0 + 4]);
                #pragma unroll
                for (int kw = 0; kw < 3; ++kw) {
                    const int kidx = c * 9 + kh * 3 + kw;
                    float wv[8];
                    *reinterpret_cast<float4*>(&wv[0]) =
                        *reinterpret_cast<const float4*>(&sW[kidx][tco * 8]);
                    *reinterpret_cast<float4*>(&wv[4]) =
                        *reinterpret_cast<const float4*>(&sW[kidx][tco * 8 + 4]);
                    #pragma unroll
                    for (int r = 0; r < 8; ++r)
                        #pragma unroll
                        for (int j = 0; j < 4; ++j)
                            acc[r][j] = fmaf(wv[r], xw[kw + j], acc[r][j]);
                }
            }
        }
    }

    // ---- epilogue: + bias, float4 stores ----
    const int h  = h0 + srow;
    const int wc = w0 + scol0;
    #pragma unroll
    for (int r = 0; r < 8; ++r) {
        const int co = co0 + tco * 8 + r;
        const float bv = bias[co];
        float4 o;
        o.x = acc[r][0] + bv;
        o.y = acc[r][1] + bv;
        o.z = acc[r][2] + bv;
        o.w = acc[r][3] + bv;
        *reinterpret_cast<float4*>(
            &y[(((size_t)n * COUT + co) * HH + h) * WW + wc]) = o;
    }
}

extern "C" void kernel_launch(void* const* d_in, const int* in_sizes, int n_in,
                              void* d_out, int out_size, void* d_ws, size_t ws_size,
                              hipStream_t stream) {
    const float* x    = (const float*)d_in[0];
    const float* wgt  = (const float*)d_in[1];
    const float* bias = (const float*)d_in[2];
    float* y          = (float*)d_out;

    const int grid = 2 * 49 * NB;   // co_tiles * spatial_tiles * batch = 3136
    conv3x3_f32<<<grid, 256, 0, stream>>>(x, wgt, bias, y);
}

// Round 3
// 385.048 us; speedup vs baseline: 4.2101x; 4.2101x over previous
//
#include <hip/hip_runtime.h>
#include <hip/hip_bf16.h>

// Conv2d 3x3 s1 p1, NCHW fp32: N=32, Cin=256, H=W=56, Cout=256.
// R3: bf16 hi/lo split (3-MFMA emulated fp32) on the matrix cores.
// Pre-pass: x -> padded NHWC bf16 hi/lo in d_ws; w -> [co][tap][ci] bf16 hi/lo.
// Main: implicit GEMM, block = 128co x 2img x (8x8 patch), 4 waves,
//       wave tile 64co x 64sp, K = 8 ci-chunks x 9 taps, MFMA 16x16x32 bf16.

#define NB   32
#define CIN  256
#define HH   56
#define WW   56
#define COUT 256

typedef unsigned short u16;
typedef __attribute__((ext_vector_type(8))) short bf16x8;   // 8 bf16 = 4 VGPR (guide §3)
typedef __attribute__((ext_vector_type(4))) float f32x4;

// ---- d_ws layout ----
#define XS_ELEMS (32u*58u*58u*256u)          // padded NHWC, per array
#define XS_BYTES ((size_t)XS_ELEMS*2u)
#define WP_ELEMS (256u*2304u)                // [co][tap9][ci256], per array
#define WP_BYTES ((size_t)WP_ELEMS*2u)
#define WS_NEED  (2u*XS_BYTES + 2u*WP_BYTES) // 112,590,848 B

__device__ __forceinline__ void gld16(const u16* g, u16* l) {
    __builtin_amdgcn_global_load_lds(
        (const __attribute__((address_space(1))) void*)g,
        (__attribute__((address_space(3))) void*)l, 16, 0, 0);
}

__device__ __forceinline__ u16 bf16_hi_bits(float v, float* hv) {
    __hip_bfloat16 hb = __float2bfloat16(v);
    *hv = __bfloat162float(hb);
    return *reinterpret_cast<u16*>(&hb);
}

// ---- pre-pass 1: x (NCHW f32) -> xs_hi/xs_lo (padded NHWC bf16) ----
__global__ __launch_bounds__(256) void xsplit(const float* __restrict__ x,
                                              u16* __restrict__ xh,
                                              u16* __restrict__ xl) {
    __shared__ float tile[32][57];
    const int t  = threadIdx.x;
    const int b  = blockIdx.x;              // n*(8*56) + cg*56 + h
    const int n  = b / (8*56);
    const int cg = (b / 56) % 8;
    const int h  = b % 56;
    const float* src = x + ((size_t)n*CIN + cg*32) * 3136 + (unsigned)h*56;
    #pragma unroll
    for (int k = 0; k < 7; ++k) {           // 32*56 = 1792 = 7*256
        int idx = t + k*256;
        int c = idx / 56, w = idx % 56;
        tile[c][w] = src[(unsigned)c*3136 + w];
    }
    __syncthreads();
    const unsigned obase = (((unsigned)n*58 + h + 1)*58 + 1)*256 + cg*32;
    #pragma unroll
    for (int k = 0; k < 7; ++k) {
        int idx = t + k*256;
        int w = idx / 32, c = idx % 32;
        float v = tile[c][w];
        float hv;
        u16 hbits = bf16_hi_bits(v, &hv);
        float r;
        u16 lbits = bf16_hi_bits(v - hv, &r);
        unsigned o = obase + (unsigned)w*256 + c;
        xh[o] = hbits;
        xl[o] = lbits;
    }
}

// ---- pre-pass 2: w (OIHW f32) -> wp_hi/wp_lo [co][tap][ci] bf16 ----
__global__ __launch_bounds__(256) void wsplit(const float* __restrict__ w,
                                              u16* __restrict__ wh,
                                              u16* __restrict__ wl) {
    unsigned i = blockIdx.x*256u + threadIdx.x;   // dst index
    if (i >= WP_ELEMS) return;
    unsigned co  = i / 2304u;
    unsigned r   = i % 2304u;
    unsigned tap = r >> 8;        // kh*3+kw
    unsigned ci  = r & 255u;
    float v = w[(size_t)co*2304u + ci*9u + tap];
    float hv;
    u16 hbits = bf16_hi_bits(v, &hv);
    float rr;
    u16 lbits = bf16_hi_bits(v - hv, &rr);
    wh[i] = hbits;
    wl[i] = lbits;
}

// ---- main conv kernel ----
__global__ __launch_bounds__(256, 3) void conv_mfma(
    const u16* __restrict__ xs_hi, const u16* __restrict__ xs_lo,
    const u16* __restrict__ wp_hi, const u16* __restrict__ wp_lo,
    const float* __restrict__ bias, float* __restrict__ y) {
    // sW: [128co][32ci]  (8KB each); sX: [2img][10r][10c][32ci] (12.8KB each)
    __shared__ __align__(16) u16 sWh[128*32], sWl[128*32];
    __shared__ __align__(16) u16 sXh[800*8],  sXl[800*8];

    const int t    = threadIdx.x;
    const int lane = t & 63, wid = t >> 6;
    const int wc   = wid >> 1;          // co half (0/1)
    const int iwv  = wid & 1;           // image   (0/1)
    const int l15  = lane & 15, kg = lane >> 4;
    const int prb  = l15 >> 3;          // 0/1 within row-pair
    const int pc   = l15 & 7;           // patch col

    const int bid  = blockIdx.x;        // (co_t*49 + sp)*16 + nt
    const int co_t = bid / (49*16);
    const int rem  = bid % (49*16);
    const int sp   = rem / 16;
    const int nt   = rem % 16;
    const int h0   = (sp / 7) * 8, w0 = (sp % 7) * 8;
    const int co0  = co_t * 128;
    const int n0   = nt * 2;

    f32x4 acc[4][4];
    #pragma unroll
    for (int m = 0; m < 4; ++m)
        #pragma unroll
        for (int j = 0; j < 4; ++j) acc[m][j] = f32x4{0.f, 0.f, 0.f, 0.f};

    for (int ck = 0; ck < 8; ++ck) {
        // stage sX for this ci-chunk: 800 16B-slots per array, lane-linear
        {
            const unsigned cko = (unsigned)ck * 32u;
            #pragma unroll
            for (int k = 0; k < 4; ++k) {
                int s = t + k*256;
                if (s < 800) {
                    int rowid = s / 40;           // 0..19
                    int rc    = s % 40;
                    int c = rc >> 2, g = rc & 3;
                    int r = rowid % 10, im = rowid / 10;
                    unsigned go = (((unsigned)(n0+im)*58u + (unsigned)(h0+r))*58u
                                   + (unsigned)(w0+c))*256u + cko + (unsigned)g*8u;
                    gld16(xs_hi + go, &sXh[(unsigned)s*8u]);
                    gld16(xs_lo + go, &sXl[(unsigned)s*8u]);
                }
            }
        }
        for (int tap = 0; tap < 9; ++tap) {
            // stage sW: 512 slots per array
            #pragma unroll
            for (int k = 0; k < 2; ++k) {
                int s = t + k*256;
                int co_l = s >> 2, g = s & 3;
                unsigned go = (unsigned)(co0+co_l)*2304u + (unsigned)tap*256u
                              + (unsigned)ck*32u + (unsigned)g*8u;
                gld16(wp_hi + go, &sWh[(unsigned)s*8u]);
                gld16(wp_lo + go, &sWl[(unsigned)s*8u]);
            }
            __syncthreads();   // compiler drains vmcnt(0) before barrier

            const int kh = tap / 3, kw = tap % 3;
            bf16x8 ah[4], al[4], bh[4], bl[4];
            #pragma unroll
            for (int m = 0; m < 4; ++m) {
                const unsigned ao = (unsigned)(wc*64 + m*16 + l15)*32u + (unsigned)kg*8u;
                ah[m] = *reinterpret_cast<const bf16x8*>(&sWh[ao]);
                al[m] = *reinterpret_cast<const bf16x8*>(&sWl[ao]);
            }
            #pragma unroll
            for (int j = 0; j < 4; ++j) {
                const int pr = 2*j + prb;
                const unsigned bo = ((unsigned)(iwv*10 + pr + kh)*10u
                                     + (unsigned)(pc + kw))*32u + (unsigned)kg*8u;
                bh[j] = *reinterpret_cast<const bf16x8*>(&sXh[bo]);
                bl[j] = *reinterpret_cast<const bf16x8*>(&sXl[bo]);
            }
            #pragma unroll
            for (int m = 0; m < 4; ++m)
                #pragma unroll
                for (int j = 0; j < 4; ++j) {
                    acc[m][j] = __builtin_amdgcn_mfma_f32_16x16x32_bf16(ah[m], bh[j], acc[m][j], 0, 0, 0);
                    acc[m][j] = __builtin_amdgcn_mfma_f32_16x16x32_bf16(ah[m], bl[j], acc[m][j], 0, 0, 0);
                    acc[m][j] = __builtin_amdgcn_mfma_f32_16x16x32_bf16(al[m], bh[j], acc[m][j], 0, 0, 0);
                }
            __syncthreads();   // protect next staging overwrite
        }
    }

    // epilogue: C/D layout col=lane&15, row=(lane>>4)*4+reg (m89-verified)
    const int n_img = n0 + iwv;
    #pragma unroll
    for (int m = 0; m < 4; ++m) {
        const int cob = co0 + wc*64 + m*16 + kg*4;
        const float4 bv = *reinterpret_cast<const float4*>(&bias[cob]);
        #pragma unroll
        for (int j = 0; j < 4; ++j) {
            const int pr = 2*j + prb;
            const unsigned yo = ((unsigned)(n_img*COUT + cob)*56u + (unsigned)(h0+pr))*56u
                                + (unsigned)(w0+pc);
            y[yo]         = acc[m][j][0] + bv.x;
            y[yo + 3136u] = acc[m][j][1] + bv.y;
            y[yo + 6272u] = acc[m][j][2] + bv.z;
            y[yo + 9408u] = acc[m][j][3] + bv.w;
        }
    }
}

// ---- fp32 fallback (R2 baseline) if ws_size is insufficient ----
#define BM 128
#define KC 8
__global__ __launch_bounds__(256, 3) void conv3x3_f32(
    const float* __restrict__ x, const float* __restrict__ wgt,
    const float* __restrict__ bias, float* __restrict__ y) {
    __shared__ float sW[KC * 9][BM];
    __shared__ float sX[KC][10][12];
    const int t = threadIdx.x;
    const int tco = t >> 4, tsp = t & 15;
    const int srow = tsp >> 1, scol0 = (tsp & 1) * 4;
    const int bid = blockIdx.x;
    const int co_t = bid / (49 * NB);
    const int rem = bid % (49 * NB);
    const int sp_t = rem / NB, n = rem % NB;
    const int h0 = (sp_t / 7) * 8, w0 = (sp_t % 7) * 8;
    const int co0 = co_t * BM;
    float acc[8][4];
    #pragma unroll
    for (int r = 0; r < 8; ++r)
        #pragma unroll
        for (int j = 0; j < 4; ++j) acc[r][j] = 0.f;
    const int co_l = t >> 1, half = t & 1;
    for (int ci0 = 0; ci0 < CIN; ci0 += KC) {
        __syncthreads();
        {
            const float4* wsrc = reinterpret_cast<const float4*>(
                wgt + (size_t)(co0 + co_l) * (CIN * 9) + ci0 * 9 + half * 36);
            #pragma unroll
            for (int q = 0; q < 9; ++q) {
                float4 v = wsrc[q];
                const int k0 = half * 36 + q * 4;
                sW[k0 + 0][co_l] = v.x; sW[k0 + 1][co_l] = v.y;
                sW[k0 + 2][co_l] = v.z; sW[k0 + 3][co_l] = v.w;
            }
        }
        for (int idx = t; idx < KC * 100; idx += 256) {
            const int c = idx / 100, r = (idx % 100) / 10, cc = idx % 10;
            const int hh = h0 + r - 1, ww = w0 + cc - 1;
            float v = 0.f;
            if (hh >= 0 && hh < HH && ww >= 0 && ww < WW)
                v = x[(((size_t)n * CIN + (ci0 + c)) * HH + hh) * WW + ww];
            sX[c][r][cc] = v;
        }
        __syncthreads();
        for (int c = 0; c < KC; ++c) {
            #pragma unroll
            for (int kh = 0; kh < 3; ++kh) {
                float xw[8];
                *reinterpret_cast<float4*>(&xw[0]) =
                    *reinterpret_cast<const float4*>(&sX[c][srow + kh][scol0]);
                *reinterpret_cast<float4*>(&xw[4]) =
                    *reinterpret_cast<const float4*>(&sX[c][srow + kh][scol0 + 4]);
                #pragma unroll
                for (int kw = 0; kw < 3; ++kw) {
                    const int kidx = c * 9 + kh * 3 + kw;
                    float wv[8];
                    *reinterpret_cast<float4*>(&wv[0]) =
                        *reinterpret_cast<const float4*>(&sW[kidx][tco * 8]);
                    *reinterpret_cast<float4*>(&wv[4]) =
                        *reinterpret_cast<const float4*>(&sW[kidx][tco * 8 + 4]);
                    #pragma unroll
                    for (int r = 0; r < 8; ++r)
                        #pragma unroll
                        for (int j = 0; j < 4; ++j)
                            acc[r][j] = fmaf(wv[r], xw[kw + j], acc[r][j]);
                }
            }
        }
    }
    const int h = h0 + srow, wc2 = w0 + scol0;
    #pragma unroll
    for (int r = 0; r < 8; ++r) {
        const int co = co0 + tco * 8 + r;
        const float bv = bias[co];
        float4 o;
        o.x = acc[r][0] + bv; o.y = acc[r][1] + bv;
        o.z = acc[r][2] + bv; o.w = acc[r][3] + bv;
        *reinterpret_cast<float4*>(
            &y[(((size_t)n * COUT + co) * HH + h) * WW + wc2]) = o;
    }
}

extern "C" void kernel_launch(void* const* d_in, const int* in_sizes, int n_in,
                              void* d_out, int out_size, void* d_ws, size_t ws_size,
                              hipStream_t stream) {
    const float* x    = (const float*)d_in[0];
    const float* wgt  = (const float*)d_in[1];
    const float* bias = (const float*)d_in[2];
    float* y          = (float*)d_out;

    if (ws_size < WS_NEED) {   // not enough scratch: fp32 baseline
        conv3x3_f32<<<2 * 49 * NB, 256, 0, stream>>>(x, wgt, bias, y);
        return;
    }

    u16* xs_hi = (u16*)d_ws;
    u16* xs_lo = xs_hi + XS_ELEMS;
    u16* wp_hi = (u16*)((char*)d_ws + 2*XS_BYTES);
    u16* wp_lo = wp_hi + WP_ELEMS;

    hipMemsetAsync(d_ws, 0, 2*XS_BYTES, stream);          // zero the halo padding
    xsplit<<<32*8*56, 256, 0, stream>>>(x, xs_hi, xs_lo);
    wsplit<<<(int)((WP_ELEMS + 255)/256), 256, 0, stream>>>(wgt, wp_hi, wp_lo);
    conv_mfma<<<2*49*16, 256, 0, stream>>>(xs_hi, xs_lo, wp_hi, wp_lo, bias, y);
}